// Round 4
// baseline (242.071 us; speedup 1.0000x reference)
//
#include <hip/hip_runtime.h>
#include <hip/hip_bf16.h>

// FeedForwardQuantum: out[b,s,e] = relu( (cos(x[b,s,:16])*cos(theta)) @ W1^T + b1 ) @ W2^T + b2
// B=16 S=4096 E=512 F=64 Q=16. Inputs fp32, OUTPUT fp32.
//
// Barrier-free / LDS-free design. 2048 blocks x 256 threads; wave w owns output cols
// [w*128, w*128+128) and 32 rows (2 unrolled iters of 16). Both GEMMs are
// mfma_f32_16x16x32_bf16:
//   MFMA1: h^T tile = (W1 .* cos(theta)) @ cos(x)^T, K=16 zero-padded to 32, b1 in C.
//   MFMA2: out tile = relu(h) @ W2^T, b2 in C.
// The second GEMM's k-slot order is the bijection f(s,quad,j) = 16*(2s+(j>>2)) + quad*4
// + (j&3), chosen so MFMA1's C-layout output (lane holds h[row=l16][f=16t+quad*4+reg])
// IS MFMA2's A-fragment after relu+bf16 pack — no LDS round-trip, no cross-lane ops,
// no __syncthreads anywhere. W2 B-frags are gathered with the same permutation.
// MFMA lane mappings validated by the round-2 runtime probe.

#define EMBED 512
#define FFN   64
#define ROWS  65536            // 16*4096
#define ROWS_PER_BLOCK 32
#define NBLOCKS (ROWS / ROWS_PER_BLOCK)   // 2048

typedef __attribute__((ext_vector_type(8))) short short8;   // 8 x bf16
typedef __attribute__((ext_vector_type(4))) float floatx4;  // mfma acc

__device__ __forceinline__ short f2bf(float f) {
    union { float f; unsigned u; } v; v.f = f;
    unsigned u = v.u;
    unsigned r = (u + 0x7fffu + ((u >> 16) & 1u)) >> 16;   // RNE
    return (short)r;
}

__device__ __forceinline__ short8 pack8(float4 a, float4 b) {
    short8 r;
    r[0] = f2bf(a.x); r[1] = f2bf(a.y); r[2] = f2bf(a.z); r[3] = f2bf(a.w);
    r[4] = f2bf(b.x); r[5] = f2bf(b.y); r[6] = f2bf(b.z); r[7] = f2bf(b.w);
    return r;
}

__global__ __launch_bounds__(256, 2)
void ffq_kernel(const float* __restrict__ x,
                const float* __restrict__ theta,
                const float* __restrict__ W1,
                const float* __restrict__ b1,
                const float* __restrict__ W2,
                const float* __restrict__ b2,
                float* __restrict__ out)
{
    const int t     = threadIdx.x;
    const int lane  = t & 63;
    const int w     = t >> 6;        // wave 0..3 -> col chunk
    const int quad  = lane >> 4;     // 0..3
    const int l16   = lane & 15;
    const int ebase = w * 128;

    // ---- one-time: A1 fragments = (W1 .* cos(theta)) in A-layout, 4 f-tiles ----
    // A1_t[m=l16][k=quad*8+j] = W1[16t+l16][q]*cos(theta[q]), q=quad*8+j (<16), else 0.
    short8 a1frag[4];
#pragma unroll
    for (int tf = 0; tf < 4; ++tf) a1frag[tf] = (short8){0,0,0,0,0,0,0,0};
    if (quad < 2) {
        float ct[8];
#pragma unroll
        for (int j = 0; j < 8; ++j) ct[j] = __cosf(theta[quad * 8 + j]);
#pragma unroll
        for (int tf = 0; tf < 4; ++tf) {
            const float4* wp = (const float4*)(W1 + (size_t)(16 * tf + l16) * 16 + quad * 8);
            float4 wa = wp[0], wb = wp[1];
            float4 pa, pb;
            pa.x = wa.x * ct[0]; pa.y = wa.y * ct[1]; pa.z = wa.z * ct[2]; pa.w = wa.w * ct[3];
            pb.x = wb.x * ct[4]; pb.y = wb.y * ct[5]; pb.z = wb.z * ct[6]; pb.w = wb.w * ct[7];
            a1frag[tf] = pack8(pa, pb);
        }
    }

    // ---- one-time: b1 C-seeds (D1 row = f = 16t + quad*4 + reg) ----
    floatx4 b1c[4];
#pragma unroll
    for (int tf = 0; tf < 4; ++tf) {
        float4 v = *(const float4*)(b1 + 16 * tf + quad * 4);
        b1c[tf] = (floatx4){v.x, v.y, v.z, v.w};
    }

    // ---- one-time: b2 per e-tile (D2 col = l16) ----
    float b2r[8];
#pragma unroll
    for (int te = 0; te < 8; ++te)
        b2r[te] = b2[ebase + te * 16 + l16];

    // ---- one-time: W2 B-fragments with permuted k-order ----
    // bfrag[te][s][j] = W2[e][16*(2s+(j>>2)) + quad*4 + (j&3)], e = ebase+te*16+l16
    short8 bfrag[8][2];
#pragma unroll
    for (int te = 0; te < 8; ++te) {
        const float* wrow = W2 + (size_t)(ebase + te * 16 + l16) * FFN;
        float4 g0 = *(const float4*)(wrow +  0 + quad * 4);
        float4 g1 = *(const float4*)(wrow + 16 + quad * 4);
        float4 g2 = *(const float4*)(wrow + 32 + quad * 4);
        float4 g3 = *(const float4*)(wrow + 48 + quad * 4);
        bfrag[te][0] = pack8(g0, g1);
        bfrag[te][1] = pack8(g2, g3);
    }

    const int rowBase = blockIdx.x * ROWS_PER_BLOCK;

#pragma unroll
    for (int it = 0; it < 2; ++it) {
        const int row0 = rowBase + it * 16;

        // ---- z fragment (B1): B1[k=quad*8+j][n=l16] = cos(x[row0+l16][q]), q<16 ----
        short8 zf = (short8){0,0,0,0,0,0,0,0};
        if (quad < 2) {
            const float4* xr = (const float4*)(x + (size_t)(row0 + l16) * EMBED + quad * 8);
            float4 xa = xr[0], xb = xr[1];
            float4 ca, cb;
            ca.x = __cosf(xa.x); ca.y = __cosf(xa.y); ca.z = __cosf(xa.z); ca.w = __cosf(xa.w);
            cb.x = __cosf(xb.x); cb.y = __cosf(xb.y); cb.z = __cosf(xb.z); cb.w = __cosf(xb.w);
            zf = pack8(ca, cb);
        }

        // ---- MFMA1: acc1[t] = h^T tile -> lane holds h[row0+l16][16t+quad*4+reg] ----
        floatx4 acc1[4];
#pragma unroll
        for (int tf = 0; tf < 4; ++tf)
            acc1[tf] = __builtin_amdgcn_mfma_f32_16x16x32_bf16(a1frag[tf], zf, b1c[tf], 0, 0, 0);

        // ---- relu + pack: MFMA1 output IS MFMA2's A-frag under the k-permutation ----
        // a2s[j] = relu(h[l16][f(s,quad,j)]) = relu(acc1[2s+(j>>2)][j&3])
        short8 a20, a21;
#pragma unroll
        for (int j = 0; j < 8; ++j) {
            a20[j] = f2bf(fmaxf(acc1[(j >> 2)][j & 3], 0.0f));
            a21[j] = f2bf(fmaxf(acc1[2 + (j >> 2)][j & 3], 0.0f));
        }

        // ---- MFMA2 + fp32 stores (D2: col=l16, row=quad*4+reg) ----
#pragma unroll
        for (int te = 0; te < 8; ++te) {
            floatx4 c = (floatx4){b2r[te], b2r[te], b2r[te], b2r[te]};
            c = __builtin_amdgcn_mfma_f32_16x16x32_bf16(a20, bfrag[te][0], c, 0, 0, 0);
            c = __builtin_amdgcn_mfma_f32_16x16x32_bf16(a21, bfrag[te][1], c, 0, 0, 0);

            float* po = out + (size_t)(row0 + quad * 4) * EMBED + ebase + te * 16 + l16;
#pragma unroll
            for (int reg = 0; reg < 4; ++reg)
                po[(size_t)reg * EMBED] = c[reg];
        }
    }
}

extern "C" void kernel_launch(void* const* d_in, const int* in_sizes, int n_in,
                              void* d_out, int out_size, void* d_ws, size_t ws_size,
                              hipStream_t stream) {
    const float* x     = (const float*)d_in[0];
    const float* theta = (const float*)d_in[1];
    const float* W1    = (const float*)d_in[2];
    const float* b1    = (const float*)d_in[3];
    const float* W2    = (const float*)d_in[4];
    const float* b2    = (const float*)d_in[5];
    float* out = (float*)d_out;

    ffq_kernel<<<NBLOCKS, 256, 0, stream>>>(x, theta, W1, b1, W2, b2, out);
}